// Round 7
// baseline (1118.672 us; speedup 1.0000x reference)
//
#include <hip/hip_runtime.h>
#include <hip/hip_bf16.h>
#include <math.h>

using bf16 = __hip_bfloat16;
typedef __attribute__((ext_vector_type(8))) short short8;
typedef __attribute__((ext_vector_type(4))) float f32x4;

constexpr int nB = 1024, nS = 30, nE = 300, nD = 512, nH = 8, nL = 4, nDK = 64;
constexpr int nTOK = nB * nS;  // 30720
constexpr float kSqrtD = 22.627416997969522f;
constexpr float kPEc   = -0.03597789207803244f;  // -2*ln(10000)/512

__device__ inline unsigned short bfbits(float f) {
  bf16 h = __float2bfloat16(f);
  return *(unsigned short*)&h;
}
__device__ inline float b2f(short s) {
  return __uint_as_float(((unsigned)(unsigned short)s) << 16);
}

// ---------------- one-shot weight convert + pe table ----------------
__global__ __launch_bounds__(256) void cvt_all(
    const float* __restrict__ Wo, const float* __restrict__ Wfc,
    const float* __restrict__ Wq, const float* __restrict__ Wk,
    const float* __restrict__ Wv, const float* __restrict__ Win,
    bf16* __restrict__ wo, bf16* __restrict__ wfc, bf16* __restrict__ wq,
    bf16* __restrict__ wk, bf16* __restrict__ wv, bf16* __restrict__ win,
    float* __restrict__ pe) {
  int i = blockIdx.x * 256 + threadIdx.x;
  if (i < 1048576) {
    wo[i] = __float2bfloat16(Wo[i]);
    wfc[i] = __float2bfloat16(Wfc[i]);
    return;
  }
  i -= 1048576;
  if (i < 16384) {
    wq[i] = __float2bfloat16(Wq[i]);
    wk[i] = __float2bfloat16(Wk[i]);
    wv[i] = __float2bfloat16(Wv[i]);
    return;
  }
  i -= 16384;
  if (i < 163840) {
    int r = i / 320, e = i - r * 320;
    win[i] = __float2bfloat16(e < nE ? Win[r * nE + e] : 0.f);
    return;
  }
  i -= 163840;
  if (i < 15360) {
    int s = i >> 9, d = i & 511;
    float ang = (float)s * expf((float)(d >> 1) * kPEc);
    pe[i] = (d & 1) ? cosf(ang) : sinf(ang);
  }
}

// gather emb rows -> bf16 [nTOK][320] (K padded 300->320 with zeros)
__global__ __launch_bounds__(256) void gather_kernel(const int* __restrict__ x,
                                                     const float* __restrict__ emb,
                                                     bf16* __restrict__ a) {
  int g = blockIdx.x * 256 + threadIdx.x;  // 30720*40 slots
  int t = g / 40, ch = g - 40 * t;
  float4 v0 = make_float4(0.f, 0.f, 0.f, 0.f), v1 = v0;
  const float* src = emb + (size_t)x[t] * nE + ch * 8;
  if (ch < 37) { v0 = *(const float4*)src; v1 = *(const float4*)(src + 4); }
  else if (ch == 37) { v0 = *(const float4*)src; }
  ushort4 u0, u1;
  u0.x = bfbits(v0.x); u0.y = bfbits(v0.y); u0.z = bfbits(v0.z); u0.w = bfbits(v0.w);
  u1.x = bfbits(v1.x); u1.y = bfbits(v1.y); u1.z = bfbits(v1.z); u1.w = bfbits(v1.w);
  bf16* dst = a + (size_t)t * 320 + ch * 8;
  *(ushort4*)dst = u0;
  *(ushort4*)(dst + 4) = u1;
}

// ---------------- LDS-free direct-MFMA GEMM: C[M,512] = A[M,KA] @ W[512,KA]^T ----------------
// Block = 128x128 tile, 4 waves in 2x2; each wave 64x64 via 4x4 MFMA subtiles.
// A,B fragments loaded straight from global (W is L2-hot, A is L3-hot). No K-loop barriers.
// LDS used only for the output transpose so stores + resid reads are coalesced.
// EPI 0: y = (acc + bias)*sqrtD + pe[row%30][col]     (embed)
// EPI 1: y = acc + bias? + resid                      (pre-LN tmp)
template <int KA, int EPI>
__global__ __launch_bounds__(256, 4) void gemm_direct(
    const bf16* __restrict__ A, const bf16* __restrict__ W,
    const float* __restrict__ bias, const bf16* __restrict__ resid,
    const float* __restrict__ pe, bf16* __restrict__ out) {
  __shared__ bf16 tb[128][132];  // 33.8 KB (fits 4 blocks/CU)
  const int tid = threadIdx.x, lane = tid & 63, w = tid >> 6;
  const int q = lane >> 4, c = lane & 15;
  const int wm = w >> 1, wn = w & 1;
  const int m0 = blockIdx.x * 128 + wm * 64;
  const int n0 = blockIdx.y * 128 + wn * 64;

  f32x4 acc[4][4];
#pragma unroll
  for (int i = 0; i < 4; ++i)
#pragma unroll
    for (int j = 0; j < 4; ++j) acc[i][j] = (f32x4){0.f, 0.f, 0.f, 0.f};

  // A-frag: lane holds A[row = m0+mt*16+c][k = ks*32 + q*8 .. +8]
  const bf16* Ap = A + (size_t)(m0 + c) * KA + q * 8;
  const bf16* Wp = W + (size_t)(n0 + c) * KA + q * 8;

#pragma unroll 2
  for (int ks = 0; ks < KA / 32; ++ks) {
    short8 af[4], bfr[4];
#pragma unroll
    for (int mt = 0; mt < 4; ++mt)
      af[mt] = *(const short8*)(Ap + (size_t)(mt * 16) * KA + ks * 32);
#pragma unroll
    for (int nt = 0; nt < 4; ++nt)
      bfr[nt] = *(const short8*)(Wp + (size_t)(nt * 16) * KA + ks * 32);
#pragma unroll
    for (int mt = 0; mt < 4; ++mt)
#pragma unroll
      for (int nt = 0; nt < 4; ++nt)
        acc[mt][nt] = __builtin_amdgcn_mfma_f32_16x16x32_bf16(af[mt], bfr[nt], acc[mt][nt], 0, 0, 0);
  }

  // scatter acc -> LDS (bf16)
#pragma unroll
  for (int mt = 0; mt < 4; ++mt)
#pragma unroll
    for (int nt = 0; nt < 4; ++nt)
#pragma unroll
      for (int r = 0; r < 4; ++r)
        tb[wm * 64 + mt * 16 + q * 4 + r][wn * 64 + nt * 16 + c] =
            __float2bfloat16(acc[mt][nt][r]);
  __syncthreads();

  // coalesced pass: thread -> (row, 64-col half)
  const int row = tid >> 1, cg = (tid & 1) * 64;
  const int gr = blockIdx.x * 128 + row;
  const int gc0 = blockIdx.y * 128 + cg;
  const int prow = gr % nS;
#pragma unroll
  for (int i = 0; i < 8; ++i) {
    const int gcol = gc0 + i * 8;
    short8 v = *(const short8*)&tb[row][cg + i * 8];
    float e[8];
#pragma unroll
    for (int j = 0; j < 8; ++j) e[j] = b2f(v[j]);
    if (bias) {
      const float4 b0 = *(const float4*)(bias + gcol);
      const float4 b1 = *(const float4*)(bias + gcol + 4);
      e[0] += b0.x; e[1] += b0.y; e[2] += b0.z; e[3] += b0.w;
      e[4] += b1.x; e[5] += b1.y; e[6] += b1.z; e[7] += b1.w;
    }
    if (EPI == 0) {
      const float4 p0 = *(const float4*)(pe + (size_t)prow * nD + gcol);
      const float4 p1 = *(const float4*)(pe + (size_t)prow * nD + gcol + 4);
      e[0] = e[0] * kSqrtD + p0.x; e[1] = e[1] * kSqrtD + p0.y;
      e[2] = e[2] * kSqrtD + p0.z; e[3] = e[3] * kSqrtD + p0.w;
      e[4] = e[4] * kSqrtD + p1.x; e[5] = e[5] * kSqrtD + p1.y;
      e[6] = e[6] * kSqrtD + p1.z; e[7] = e[7] * kSqrtD + p1.w;
    } else {
      short8 rv = *(const short8*)(resid + (size_t)gr * nD + gcol);
#pragma unroll
      for (int j = 0; j < 8; ++j) e[j] += b2f(rv[j]);
    }
    short8 o;
#pragma unroll
    for (int j = 0; j < 8; ++j) o[j] = (short)bfbits(e[j]);
    *(short8*)(out + (size_t)gr * nD + gcol) = o;
  }
}

// ---------------- row LayerNorm over D=512, bf16 in, bf16 (or final fp32) out ----------------
template <int FINAL>
__global__ __launch_bounds__(256) void ln_bf(
    const bf16* __restrict__ X, const float* __restrict__ g,
    const float* __restrict__ bta, bf16* __restrict__ yb,
    float* __restrict__ yf) {
  const int w = threadIdx.x >> 6, lane = threadIdx.x & 63;
  const int row = blockIdx.x * 4 + w;
  short8 v = *(const short8*)(X + (size_t)row * nD + lane * 8);
  float e[8];
  float s = 0.f, sq = 0.f;
#pragma unroll
  for (int j = 0; j < 8; ++j) {
    e[j] = b2f(v[j]);
    s += e[j]; sq += e[j] * e[j];
  }
#pragma unroll
  for (int off = 1; off < 64; off <<= 1) {
    s += __shfl_xor(s, off);
    sq += __shfl_xor(sq, off);
  }
  const float mu = s * (1.f / nD);
  const float var = sq * (1.f / nD) - mu * mu;
  const float inv = rsqrtf(var + 1e-5f);
  const float4 g0 = *(const float4*)(g + lane * 8);
  const float4 g1 = *(const float4*)(g + lane * 8 + 4);
  const float4 b0 = *(const float4*)(bta + lane * 8);
  const float4 b1 = *(const float4*)(bta + lane * 8 + 4);
  float y[8];
  y[0] = (e[0] - mu) * inv * g0.x + b0.x;
  y[1] = (e[1] - mu) * inv * g0.y + b0.y;
  y[2] = (e[2] - mu) * inv * g0.z + b0.z;
  y[3] = (e[3] - mu) * inv * g0.w + b0.w;
  y[4] = (e[4] - mu) * inv * g1.x + b1.x;
  y[5] = (e[5] - mu) * inv * g1.y + b1.y;
  y[6] = (e[6] - mu) * inv * g1.z + b1.z;
  y[7] = (e[7] - mu) * inv * g1.w + b1.w;
  if (FINAL) {
    float* p = yf + (size_t)row * nD + lane * 8;
    *(float4*)p = make_float4(y[0], y[1], y[2], y[3]);
    *(float4*)(p + 4) = make_float4(y[4], y[5], y[6], y[7]);
  } else {
    short8 o;
#pragma unroll
    for (int j = 0; j < 8; ++j) o[j] = (short)bfbits(y[j]);
    *(short8*)(yb + (size_t)row * nD + lane * 8) = o;
  }
}

// ---------------- fully fused attention per (batch, head), MFMA ----------------
__global__ __launch_bounds__(256) void attn_kernel(
    const bf16* __restrict__ wqb, const bf16* __restrict__ wkb,
    const bf16* __restrict__ wvb, const int* __restrict__ mask,
    const bf16* __restrict__ hin, bf16* __restrict__ aout) {
  const int tid = threadIdx.x, lane = tid & 63, w = tid >> 6;
  const int q = lane >> 4, c = lane & 15;
  const int b = blockIdx.x >> 3, hd = blockIdx.x & 7;

  __shared__ __align__(16) bf16 xs[8][32][8];
  __shared__ __align__(16) bf16 wq[8][64][8];
  __shared__ __align__(16) bf16 wk[8][64][8];
  __shared__ __align__(16) bf16 wv[8][64][8];
  __shared__ __align__(16) bf16 qb[8][32][8];
  __shared__ __align__(16) bf16 kb[8][32][8];
  __shared__ __align__(16) bf16 vt[4][64][8];
  __shared__ __align__(16) bf16 pb[4][32][8];
  __shared__ float ps[32][33];
  __shared__ int msk[32];

  {  // stage x (pad rows 30,31 with zeros)
    int row = tid & 31, k8 = tid >> 5;
    uint4 z = make_uint4(0, 0, 0, 0);
    if (row < nS)
      z = *(const uint4*)(hin + (size_t)(b * nS + row) * nD + hd * nDK + k8 * 8);
    *(uint4*)&xs[k8][row][0] = z;
  }
#pragma unroll
  for (int i = 0; i < 2; ++i) {
    int s = tid + i * 256;
    int row = s & 63, k8 = s >> 6;
    *(uint4*)&wq[k8][row][0] = *(const uint4*)(wqb + row * 64 + k8 * 8);
    *(uint4*)&wk[k8][row][0] = *(const uint4*)(wkb + row * 64 + k8 * 8);
    *(uint4*)&wv[k8][row][0] = *(const uint4*)(wvb + row * 64 + k8 * 8);
  }
  if (tid < nS) msk[tid] = mask[b * nS + tid];
  __syncthreads();

  f32x4 aq[2], ak[2], av[2];
#pragma unroll
  for (int mt = 0; mt < 2; ++mt) {
    aq[mt] = (f32x4){0.f, 0.f, 0.f, 0.f};
    ak[mt] = aq[mt]; av[mt] = aq[mt];
  }
#pragma unroll
  for (int kc = 0; kc < 2; ++kc) {
    short8 xa0 = *(const short8*)&xs[kc * 4 + q][c][0];
    short8 xa1 = *(const short8*)&xs[kc * 4 + q][16 + c][0];
    short8 wqf = *(const short8*)&wq[kc * 4 + q][w * 16 + c][0];
    short8 wkf = *(const short8*)&wk[kc * 4 + q][w * 16 + c][0];
    short8 wvf = *(const short8*)&wv[kc * 4 + q][w * 16 + c][0];
    aq[0] = __builtin_amdgcn_mfma_f32_16x16x32_bf16(xa0, wqf, aq[0], 0, 0, 0);
    aq[1] = __builtin_amdgcn_mfma_f32_16x16x32_bf16(xa1, wqf, aq[1], 0, 0, 0);
    ak[0] = __builtin_amdgcn_mfma_f32_16x16x32_bf16(xa0, wkf, ak[0], 0, 0, 0);
    ak[1] = __builtin_amdgcn_mfma_f32_16x16x32_bf16(xa1, wkf, ak[1], 0, 0, 0);
    av[0] = __builtin_amdgcn_mfma_f32_16x16x32_bf16(xa0, wvf, av[0], 0, 0, 0);
    av[1] = __builtin_amdgcn_mfma_f32_16x16x32_bf16(xa1, wvf, av[1], 0, 0, 0);
  }
  const int dk = w * 16 + c;
#pragma unroll
  for (int mt = 0; mt < 2; ++mt)
#pragma unroll
    for (int r = 0; r < 4; ++r) {
      int i = mt * 16 + q * 4 + r;
      qb[dk >> 3][i][dk & 7] = __float2bfloat16(aq[mt][r]);
      kb[dk >> 3][i][dk & 7] = __float2bfloat16(ak[mt][r]);
      vt[i >> 3][dk][i & 7] = __float2bfloat16(av[mt][r]);
    }
  __syncthreads();

  {
    f32x4 sc = (f32x4){0.f, 0.f, 0.f, 0.f};
    const int is0 = (w >> 1) * 16, js0 = (w & 1) * 16;
#pragma unroll
    for (int kc = 0; kc < 2; ++kc) {
      short8 a = *(const short8*)&qb[kc * 4 + q][is0 + c][0];
      short8 bb = *(const short8*)&kb[kc * 4 + q][js0 + c][0];
      sc = __builtin_amdgcn_mfma_f32_16x16x32_bf16(a, bb, sc, 0, 0, 0);
    }
    int j = js0 + c;
    bool live = (j < nS) && (msk[j] != 0);
#pragma unroll
    for (int r = 0; r < 4; ++r) {
      int i = is0 + q * 4 + r;
      ps[i][j] = live ? sc[r] * 0.125f : -1e9f;
    }
  }
  __syncthreads();

  if (tid < nS * 8) {
    int r = tid >> 3, cc = tid & 7;
    float m = -1e30f;
    for (int j = cc; j < nS; j += 8) m = fmaxf(m, ps[r][j]);
#pragma unroll
    for (int o = 1; o < 8; o <<= 1) m = fmaxf(m, __shfl_xor(m, o));
    float sum = 0.f;
    for (int j = cc; j < nS; j += 8) sum += __expf(ps[r][j] - m);
#pragma unroll
    for (int o = 1; o < 8; o <<= 1) sum += __shfl_xor(sum, o);
    float inv = 1.f / sum;
    for (int j = cc; j < nS; j += 8)
      pb[j >> 3][r][j & 7] = __float2bfloat16(__expf(ps[r][j] - m) * inv);
    if (cc >= 6) pb[3][r][cc] = __float2bfloat16(0.f);
  }
  __syncthreads();

  {
    f32x4 o0 = (f32x4){0.f, 0.f, 0.f, 0.f}, o1 = o0;
    short8 pa0 = *(const short8*)&pb[q][c][0];
    short8 pa1 = *(const short8*)&pb[q][16 + c][0];
    short8 vb = *(const short8*)&vt[q][w * 16 + c][0];
    o0 = __builtin_amdgcn_mfma_f32_16x16x32_bf16(pa0, vb, o0, 0, 0, 0);
    o1 = __builtin_amdgcn_mfma_f32_16x16x32_bf16(pa1, vb, o1, 0, 0, 0);
#pragma unroll
    for (int r = 0; r < 4; ++r) {
      int i0 = q * 4 + r;
      aout[(size_t)(b * nS + i0) * nD + hd * nDK + dk] = __float2bfloat16(o0[r]);
      int i1 = 16 + q * 4 + r;
      if (i1 < nS)
        aout[(size_t)(b * nS + i1) * nD + hd * nDK + dk] = __float2bfloat16(o1[r]);
    }
  }
}

extern "C" void kernel_launch(void* const* d_in, const int* in_sizes, int n_in,
                              void* d_out, int out_size, void* d_ws, size_t ws_size,
                              hipStream_t stream) {
  const int*   x    = (const int*)d_in[0];
  const int*   mask = (const int*)d_in[1];
  const float* emb  = (const float*)d_in[2];
  const float* W_in = (const float*)d_in[3];
  const float* b_in = (const float*)d_in[4];
  const float* Wq   = (const float*)d_in[5];
  const float* Wk   = (const float*)d_in[6];
  const float* Wv   = (const float*)d_in[7];
  const float* Wo   = (const float*)d_in[8];
  const float* Wfc  = (const float*)d_in[9];
  const float* bfc  = (const float*)d_in[10];
  const float* g1   = (const float*)d_in[11];
  const float* be1  = (const float*)d_in[12];
  const float* g2   = (const float*)d_in[13];
  const float* be2  = (const float*)d_in[14];

  char* ws = (char*)d_ws;
  bf16* wo_b  = (bf16*)ws;                    // 2,097,152 B
  bf16* wfc_b = (bf16*)(ws + 2097152);        // 2,097,152
  bf16* wq_b  = (bf16*)(ws + 4194304);        // 32,768
  bf16* wk_b  = (bf16*)(ws + 4227072);        // 32,768
  bf16* wv_b  = (bf16*)(ws + 4259840);        // 32,768
  bf16* win_b = (bf16*)(ws + 4292608);        // 327,680
  float* pe   = (float*)(ws + 4620288);       // 61,440
  bf16* a_emb = (bf16*)(ws + 4681728);        // 19,660,800
  bf16* cur   = (bf16*)(ws + 24342528);       // 31,457,280  (h, bf16)
  bf16* o_buf = (bf16*)(ws + 55799808);       // 31,457,280
  bf16* t1    = (bf16*)(ws + 87257088);       // 31,457,280

  cvt_all<<<4860, 256, 0, stream>>>(Wo, Wfc, Wq, Wk, Wv, W_in, wo_b, wfc_b,
                                    wq_b, wk_b, wv_b, win_b, pe);
  gather_kernel<<<4800, 256, 0, stream>>>(x, emb, a_emb);

  const dim3 ggrid(nTOK / 128, nD / 128);  // (240, 4)
  // h0 = (emb@Win + b_in)*sqrtD + pe
  gemm_direct<320, 0><<<ggrid, 256, 0, stream>>>(a_emb, win_b, b_in, nullptr, pe, cur);

  for (int l = 0; l < nL; ++l) {
    attn_kernel<<<nB * nH, 256, 0, stream>>>(wq_b + l * 4096, wk_b + l * 4096,
                                             wv_b + l * 4096, mask, cur, o_buf);
    // t1 = o @ Wo^T + cur
    gemm_direct<512, 1><<<ggrid, 256, 0, stream>>>(
        o_buf, wo_b + (size_t)l * 262144, nullptr, cur, nullptr, t1);
    ln_bf<0><<<nTOK / 4, 256, 0, stream>>>(t1, g1 + l * nD, be1 + l * nD, t1, nullptr);
    // cur' = n1 @ Wfc^T + bfc + n1   (cur is dead, overwrite)
    gemm_direct<512, 1><<<ggrid, 256, 0, stream>>>(
        t1, wfc_b + (size_t)l * 262144, bfc + l * nD, t1, nullptr, cur);
    if (l < nL - 1) {
      ln_bf<0><<<nTOK / 4, 256, 0, stream>>>(cur, g2 + l * nD, be2 + l * nD, cur, nullptr);
    } else {
      ln_bf<1><<<nTOK / 4, 256, 0, stream>>>(cur, g2 + l * nD, be2 + l * nD,
                                             nullptr, (float*)d_out);
    }
  }
  (void)in_sizes; (void)n_in; (void)out_size; (void)ws_size;
}

// Round 8
// 636.912 us; speedup vs baseline: 1.7564x; 1.7564x over previous
//
#include <hip/hip_runtime.h>
#include <hip/hip_bf16.h>
#include <math.h>

using bf16 = __hip_bfloat16;
typedef __attribute__((ext_vector_type(8))) short short8;
typedef __attribute__((ext_vector_type(4))) float f32x4;

constexpr int nB = 1024, nS = 30, nE = 300, nD = 512, nH = 8, nL = 4, nDK = 64;
constexpr int nTOK = nB * nS;  // 30720
constexpr float kSqrtD = 22.627416997969522f;    // sqrt(512)
constexpr float kPEc   = -0.03597789207803244f;  // -2*ln(10000)/512

__device__ inline unsigned short bfbits(float f) {
  bf16 h = __float2bfloat16(f);
  return *(unsigned short*)&h;
}
__device__ inline float b2f(short s) {
  return __uint_as_float(((unsigned)(unsigned short)s) << 16);
}
__device__ inline void gload16(const void* g, void* lds) {
  __builtin_amdgcn_global_load_lds(
      (const __attribute__((address_space(1))) unsigned int*)g,
      (__attribute__((address_space(3))) unsigned int*)lds, 16, 0, 0);
}

// ---------------- one-shot weight convert + pe table ----------------
__global__ __launch_bounds__(256) void cvt_all(
    const float* __restrict__ Wo, const float* __restrict__ Wfc,
    const float* __restrict__ Wq, const float* __restrict__ Wk,
    const float* __restrict__ Wv, const float* __restrict__ Win,
    bf16* __restrict__ wo, bf16* __restrict__ wfc, bf16* __restrict__ wq,
    bf16* __restrict__ wk, bf16* __restrict__ wv, bf16* __restrict__ win,
    float* __restrict__ pe) {
  int i = blockIdx.x * 256 + threadIdx.x;
  if (i < 1048576) {
    wo[i] = __float2bfloat16(Wo[i]);
    wfc[i] = __float2bfloat16(Wfc[i]);
    return;
  }
  i -= 1048576;
  if (i < 16384) {
    wq[i] = __float2bfloat16(Wq[i]);
    wk[i] = __float2bfloat16(Wk[i]);
    wv[i] = __float2bfloat16(Wv[i]);
    return;
  }
  i -= 16384;
  if (i < 163840) {
    int r = i / 320, e = i - r * 320;
    win[i] = __float2bfloat16(e < nE ? Win[r * nE + e] : 0.f);
    return;
  }
  i -= 163840;
  if (i < 15360) {
    int s = i >> 9, d = i & 511;
    float ang = (float)s * expf((float)(d >> 1) * kPEc);
    pe[i] = (d & 1) ? cosf(ang) : sinf(ang);
  }
}

// gather emb rows -> bf16 [nTOK][320] (K padded 300->320 with zeros)
__global__ __launch_bounds__(256) void gather_kernel(const int* __restrict__ x,
                                                     const float* __restrict__ emb,
                                                     bf16* __restrict__ a) {
  int g = blockIdx.x * 256 + threadIdx.x;  // 30720*40 slots
  int t = g / 40, ch = g - 40 * t;
  float4 v0 = make_float4(0.f, 0.f, 0.f, 0.f), v1 = v0;
  const float* src = emb + (size_t)x[t] * nE + ch * 8;
  if (ch < 37) { v0 = *(const float4*)src; v1 = *(const float4*)(src + 4); }
  else if (ch == 37) { v0 = *(const float4*)src; }
  ushort4 u0, u1;
  u0.x = bfbits(v0.x); u0.y = bfbits(v0.y); u0.z = bfbits(v0.z); u0.w = bfbits(v0.w);
  u1.x = bfbits(v1.x); u1.y = bfbits(v1.y); u1.z = bfbits(v1.z); u1.w = bfbits(v1.w);
  bf16* dst = a + (size_t)t * 320 + ch * 8;
  *(ushort4*)dst = u0;
  *(ushort4*)(dst + 4) = u1;
}

// ---------------- fused MFMA GEMM: C[M,512] = A[M,KA](bf16) @ W[512,KA](bf16)^T ----------------
// R3 structure (64 rows x full N=512, gload_lds staging, fused LN epilogue),
// bf16-only streams: resid read bf16; output bf16, or fp32 (FIN=1, final LN2 -> d_out).
// EPI 0: y = (acc + bias)*sqrtD + pe[row%30][col]          (embed)
// EPI 1: y = LN(acc + bias? + resid)[g,beta]               (transformer)
template <int KA, int EPI, int FIN>
__global__ __launch_bounds__(256, 2) void gemm_fused(
    const bf16* __restrict__ A, const bf16* __restrict__ W,
    const float* __restrict__ bias, const bf16* __restrict__ resid,
    const float* __restrict__ pe, const float* __restrict__ g,
    const float* __restrict__ beta, float* __restrict__ outf,
    bf16* __restrict__ outb) {
  __shared__ __align__(16) char smem[39424];
  bf16* As = (bf16*)smem;            // [4][64][8] chunked
  bf16* Ws = (bf16*)smem + 2048;     // [4][512][8]
  float* tb = (float*)smem;          // epilogue transpose, wave w: [w*2048 .. +2048)
  float* stats = (float*)(smem + 36864);   // [64][4][2]
  float* stats2 = (float*)(smem + 38912);  // [64][2] (mu, inv)

  const int tid = threadIdx.x, lane = tid & 63, w = tid >> 6;
  const int q = lane >> 4, c = lane & 15;
  const int m0 = blockIdx.x * 64;

  f32x4 acc[4][8];
#pragma unroll
  for (int i = 0; i < 4; ++i)
#pragma unroll
    for (int j = 0; j < 8; ++j) acc[i][j] = (f32x4){0.f, 0.f, 0.f, 0.f};

  const bf16* Ag = A + (size_t)(m0 + lane) * KA + w * 8;  // row m0+lane, k-chunk w
  const bf16* Wg = W + (size_t)lane * KA + w * 8;
  bf16* AsDst = As + (w * 64) * 8;
  bf16* WsDst = Ws + (w * 512) * 8;

  for (int ks = 0; ks < KA / 32; ++ks) {
    __syncthreads();
    gload16(Ag + ks * 32, AsDst);
#pragma unroll
    for (int j = 0; j < 8; ++j)
      gload16(Wg + (size_t)(j * 64) * KA + ks * 32, WsDst + j * 64 * 8);
    __syncthreads();
    short8 af[4], bfr[8];
#pragma unroll
    for (int mt = 0; mt < 4; ++mt)
      af[mt] = *(const short8*)(As + (q * 64 + mt * 16 + c) * 8);
#pragma unroll
    for (int nt = 0; nt < 8; ++nt)
      bfr[nt] = *(const short8*)(Ws + (q * 512 + w * 128 + nt * 16 + c) * 8);
#pragma unroll
    for (int mt = 0; mt < 4; ++mt)
#pragma unroll
      for (int nt = 0; nt < 8; ++nt)
        acc[mt][nt] = __builtin_amdgcn_mfma_f32_16x16x32_bf16(af[mt], bfr[nt], acc[mt][nt], 0, 0, 0);
  }

  // ---- epilogue ----
  float bias4[8];
#pragma unroll
  for (int nt = 0; nt < 8; ++nt)
    bias4[nt] = bias ? bias[w * 128 + nt * 16 + c] : 0.f;

  if (EPI == 0) {
#pragma unroll
    for (int mt = 0; mt < 4; ++mt)
#pragma unroll
      for (int r = 0; r < 4; ++r) {
        int m = m0 + mt * 16 + q * 4 + r;
        int s = m % nS;
        const float* pes = pe + (size_t)s * nD + w * 128 + c;
#pragma unroll
        for (int nt = 0; nt < 8; ++nt)
          acc[mt][nt][r] = (acc[mt][nt][r] + bias4[nt]) * kSqrtD + pes[nt * 16];
      }
    __syncthreads();  // LDS now free for transpose reuse
  } else {
    float rs[4][4], rq[4][4];
#pragma unroll
    for (int mt = 0; mt < 4; ++mt)
#pragma unroll
      for (int r = 0; r < 4; ++r) {
        int m = m0 + mt * 16 + q * 4 + r;
        const short* rp = (const short*)(resid + (size_t)m * nD + w * 128 + c);
        float s1 = 0.f, s2 = 0.f;
#pragma unroll
        for (int nt = 0; nt < 8; ++nt) {
          float t = acc[mt][nt][r] + bias4[nt] + b2f(rp[nt * 16]);
          acc[mt][nt][r] = t;
          s1 += t; s2 += t * t;
        }
        rs[mt][r] = s1; rq[mt][r] = s2;
      }
#pragma unroll
    for (int mt = 0; mt < 4; ++mt)
#pragma unroll
      for (int r = 0; r < 4; ++r)
#pragma unroll
        for (int off = 1; off < 16; off <<= 1) {
          rs[mt][r] += __shfl_xor(rs[mt][r], off);
          rq[mt][r] += __shfl_xor(rq[mt][r], off);
        }
#pragma unroll
    for (int mt = 0; mt < 4; ++mt)
#pragma unroll
      for (int r = 0; r < 4; ++r)
        if (c == mt * 4 + r) {
          int row = mt * 16 + q * 4 + r;
          stats[row * 8 + w * 2] = rs[mt][r];
          stats[row * 8 + w * 2 + 1] = rq[mt][r];
        }
    __syncthreads();
    if (tid < 64) {
      float su = 0.f, sq = 0.f;
#pragma unroll
      for (int ww = 0; ww < 4; ++ww) {
        su += stats[tid * 8 + ww * 2];
        sq += stats[tid * 8 + ww * 2 + 1];
      }
      float mu = su * (1.f / nD);
      float var = sq * (1.f / nD) - mu * mu;
      stats2[tid * 2] = mu;
      stats2[tid * 2 + 1] = rsqrtf(var + 1e-5f);
    }
    __syncthreads();
  }

  // transpose + coalesced single store (bf16, or fp32 when FIN)
  float* tbw = tb + w * 2048;
  const int l32 = lane & 31, hi = lane >> 5;
  const int colw = w * 128 + l32 * 4;
  float4 g4 = make_float4(0, 0, 0, 0), be4 = g4;
  if (EPI == 1) {
    g4 = *(const float4*)&g[colw];
    be4 = *(const float4*)&beta[colw];
  }
#pragma unroll
  for (int mt = 0; mt < 4; ++mt) {
#pragma unroll
    for (int nt = 0; nt < 8; ++nt)
#pragma unroll
      for (int r = 0; r < 4; ++r)
        tbw[(q * 4 + r) * 128 + nt * 16 + c] = acc[mt][nt][r];
#pragma unroll
    for (int i = 0; i < 8; ++i) {
      float4 v = *(const float4*)&tbw[(i * 64 + lane) * 4];
      int rl = mt * 16 + i * 2 + hi;
      int m = m0 + rl;
      float4 y;
      if (EPI == 1) {
        float mu = stats2[rl * 2], inv = stats2[rl * 2 + 1];
        y.x = (v.x - mu) * inv * g4.x + be4.x;
        y.y = (v.y - mu) * inv * g4.y + be4.y;
        y.z = (v.z - mu) * inv * g4.z + be4.z;
        y.w = (v.w - mu) * inv * g4.w + be4.w;
      } else {
        y = v;
      }
      if (FIN) {
        *(float4*)(outf + (size_t)m * nD + colw) = y;
      } else {
        ushort4 ub;
        ub.x = bfbits(y.x); ub.y = bfbits(y.y); ub.z = bfbits(y.z); ub.w = bfbits(y.w);
        *(ushort4*)(outb + (size_t)m * nD + colw) = ub;
      }
    }
  }
}

// ---------------- fully fused attention per (batch, head), MFMA ----------------
__global__ __launch_bounds__(256) void attn_kernel(
    const bf16* __restrict__ wqb, const bf16* __restrict__ wkb,
    const bf16* __restrict__ wvb, const int* __restrict__ mask,
    const bf16* __restrict__ hin, bf16* __restrict__ aout) {
  const int tid = threadIdx.x, lane = tid & 63, w = tid >> 6;
  const int q = lane >> 4, c = lane & 15;
  const int b = blockIdx.x >> 3, hd = blockIdx.x & 7;

  __shared__ __align__(16) bf16 xs[8][32][8];
  __shared__ __align__(16) bf16 wq[8][64][8];
  __shared__ __align__(16) bf16 wk[8][64][8];
  __shared__ __align__(16) bf16 wv[8][64][8];
  __shared__ __align__(16) bf16 qb[8][32][8];
  __shared__ __align__(16) bf16 kb[8][32][8];
  __shared__ __align__(16) bf16 vt[4][64][8];
  __shared__ __align__(16) bf16 pb[4][32][8];
  __shared__ float ps[32][33];
  __shared__ int msk[32];

  {  // stage x (pad rows 30,31 with zeros)
    int row = tid & 31, k8 = tid >> 5;
    uint4 z = make_uint4(0, 0, 0, 0);
    if (row < nS)
      z = *(const uint4*)(hin + (size_t)(b * nS + row) * nD + hd * nDK + k8 * 8);
    *(uint4*)&xs[k8][row][0] = z;
  }
#pragma unroll
  for (int i = 0; i < 2; ++i) {
    int s = tid + i * 256;
    int row = s & 63, k8 = s >> 6;
    *(uint4*)&wq[k8][row][0] = *(const uint4*)(wqb + row * 64 + k8 * 8);
    *(uint4*)&wk[k8][row][0] = *(const uint4*)(wkb + row * 64 + k8 * 8);
    *(uint4*)&wv[k8][row][0] = *(const uint4*)(wvb + row * 64 + k8 * 8);
  }
  if (tid < nS) msk[tid] = mask[b * nS + tid];
  __syncthreads();

  f32x4 aq[2], ak[2], av[2];
#pragma unroll
  for (int mt = 0; mt < 2; ++mt) {
    aq[mt] = (f32x4){0.f, 0.f, 0.f, 0.f};
    ak[mt] = aq[mt]; av[mt] = aq[mt];
  }
#pragma unroll
  for (int kc = 0; kc < 2; ++kc) {
    short8 xa0 = *(const short8*)&xs[kc * 4 + q][c][0];
    short8 xa1 = *(const short8*)&xs[kc * 4 + q][16 + c][0];
    short8 wqf = *(const short8*)&wq[kc * 4 + q][w * 16 + c][0];
    short8 wkf = *(const short8*)&wk[kc * 4 + q][w * 16 + c][0];
    short8 wvf = *(const short8*)&wv[kc * 4 + q][w * 16 + c][0];
    aq[0] = __builtin_amdgcn_mfma_f32_16x16x32_bf16(xa0, wqf, aq[0], 0, 0, 0);
    aq[1] = __builtin_amdgcn_mfma_f32_16x16x32_bf16(xa1, wqf, aq[1], 0, 0, 0);
    ak[0] = __builtin_amdgcn_mfma_f32_16x16x32_bf16(xa0, wkf, ak[0], 0, 0, 0);
    ak[1] = __builtin_amdgcn_mfma_f32_16x16x32_bf16(xa1, wkf, ak[1], 0, 0, 0);
    av[0] = __builtin_amdgcn_mfma_f32_16x16x32_bf16(xa0, wvf, av[0], 0, 0, 0);
    av[1] = __builtin_amdgcn_mfma_f32_16x16x32_bf16(xa1, wvf, av[1], 0, 0, 0);
  }
  const int dk = w * 16 + c;
#pragma unroll
  for (int mt = 0; mt < 2; ++mt)
#pragma unroll
    for (int r = 0; r < 4; ++r) {
      int i = mt * 16 + q * 4 + r;
      qb[dk >> 3][i][dk & 7] = __float2bfloat16(aq[mt][r]);
      kb[dk >> 3][i][dk & 7] = __float2bfloat16(ak[mt][r]);
      vt[i >> 3][dk][i & 7] = __float2bfloat16(av[mt][r]);
    }
  __syncthreads();

  {
    f32x4 sc = (f32x4){0.f, 0.f, 0.f, 0.f};
    const int is0 = (w >> 1) * 16, js0 = (w & 1) * 16;
#pragma unroll
    for (int kc = 0; kc < 2; ++kc) {
      short8 a = *(const short8*)&qb[kc * 4 + q][is0 + c][0];
      short8 bb = *(const short8*)&kb[kc * 4 + q][js0 + c][0];
      sc = __builtin_amdgcn_mfma_f32_16x16x32_bf16(a, bb, sc, 0, 0, 0);
    }
    int j = js0 + c;
    bool live = (j < nS) && (msk[j] != 0);
#pragma unroll
    for (int r = 0; r < 4; ++r) {
      int i = is0 + q * 4 + r;
      ps[i][j] = live ? sc[r] * 0.125f : -1e9f;
    }
  }
  __syncthreads();

  if (tid < nS * 8) {
    int r = tid >> 3, cc = tid & 7;
    float m = -1e30f;
    for (int j = cc; j < nS; j += 8) m = fmaxf(m, ps[r][j]);
#pragma unroll
    for (int o = 1; o < 8; o <<= 1) m = fmaxf(m, __shfl_xor(m, o));
    float sum = 0.f;
    for (int j = cc; j < nS; j += 8) sum += __expf(ps[r][j] - m);
#pragma unroll
    for (int o = 1; o < 8; o <<= 1) sum += __shfl_xor(sum, o);
    float inv = 1.f / sum;
    for (int j = cc; j < nS; j += 8)
      pb[j >> 3][r][j & 7] = __float2bfloat16(__expf(ps[r][j] - m) * inv);
    if (cc >= 6) pb[3][r][cc] = __float2bfloat16(0.f);
  }
  __syncthreads();

  {
    f32x4 o0 = (f32x4){0.f, 0.f, 0.f, 0.f}, o1 = o0;
    short8 pa0 = *(const short8*)&pb[q][c][0];
    short8 pa1 = *(const short8*)&pb[q][16 + c][0];
    short8 vb = *(const short8*)&vt[q][w * 16 + c][0];
    o0 = __builtin_amdgcn_mfma_f32_16x16x32_bf16(pa0, vb, o0, 0, 0, 0);
    o1 = __builtin_amdgcn_mfma_f32_16x16x32_bf16(pa1, vb, o1, 0, 0, 0);
#pragma unroll
    for (int r = 0; r < 4; ++r) {
      int i0 = q * 4 + r;
      aout[(size_t)(b * nS + i0) * nD + hd * nDK + dk] = __float2bfloat16(o0[r]);
      int i1 = 16 + q * 4 + r;
      if (i1 < nS)
        aout[(size_t)(b * nS + i1) * nD + hd * nDK + dk] = __float2bfloat16(o1[r]);
    }
  }
}

extern "C" void kernel_launch(void* const* d_in, const int* in_sizes, int n_in,
                              void* d_out, int out_size, void* d_ws, size_t ws_size,
                              hipStream_t stream) {
  const int*   x    = (const int*)d_in[0];
  const int*   mask = (const int*)d_in[1];
  const float* emb  = (const float*)d_in[2];
  const float* W_in = (const float*)d_in[3];
  const float* b_in = (const float*)d_in[4];
  const float* Wq   = (const float*)d_in[5];
  const float* Wk   = (const float*)d_in[6];
  const float* Wv   = (const float*)d_in[7];
  const float* Wo   = (const float*)d_in[8];
  const float* Wfc  = (const float*)d_in[9];
  const float* bfc  = (const float*)d_in[10];
  const float* g1   = (const float*)d_in[11];
  const float* be1  = (const float*)d_in[12];
  const float* g2   = (const float*)d_in[13];
  const float* be2  = (const float*)d_in[14];

  char* ws = (char*)d_ws;
  bf16* wo_b  = (bf16*)ws;                    // 2,097,152 B
  bf16* wfc_b = (bf16*)(ws + 2097152);        // 2,097,152
  bf16* wq_b  = (bf16*)(ws + 4194304);        // 32,768
  bf16* wk_b  = (bf16*)(ws + 4227072);        // 32,768
  bf16* wv_b  = (bf16*)(ws + 4259840);        // 32,768
  bf16* win_b = (bf16*)(ws + 4292608);        // 327,680
  float* pe   = (float*)(ws + 4620288);       // 61,440
  bf16* a_emb = (bf16*)(ws + 4681728);        // 19,660,800
  bf16* bufH  = (bf16*)(ws + 24342528);       // 31,457,280  h / h'
  bf16* bufO  = (bf16*)(ws + 55799808);       // 31,457,280  attn out
  bf16* bufN  = (bf16*)(ws + 87257088);       // 31,457,280  n1

  cvt_all<<<4860, 256, 0, stream>>>(Wo, Wfc, Wq, Wk, Wv, W_in, wo_b, wfc_b,
                                    wq_b, wk_b, wv_b, win_b, pe);
  gather_kernel<<<4800, 256, 0, stream>>>(x, emb, a_emb);

  // h0 = (emb@Win + b_in)*sqrtD + pe  -> bufH (bf16)
  gemm_fused<320, 0, 0><<<480, 256, 0, stream>>>(
      a_emb, win_b, b_in, nullptr, pe, nullptr, nullptr, nullptr, bufH);

  for (int l = 0; l < nL; ++l) {
    attn_kernel<<<nB * nH, 256, 0, stream>>>(
        wq_b + l * 4096, wk_b + l * 4096, wv_b + l * 4096, mask, bufH, bufO);
    // n1 = LN1(o @ Wo^T + h)  -> bufN
    gemm_fused<512, 1, 0><<<480, 256, 0, stream>>>(
        bufO, wo_b + (size_t)l * 262144, nullptr, bufH, nullptr, g1 + l * nD,
        be1 + l * nD, nullptr, bufN);
    if (l < nL - 1) {
      // h' = LN2(n1 @ Wfc^T + bfc + n1)  -> bufH (dead)
      gemm_fused<512, 1, 0><<<480, 256, 0, stream>>>(
          bufN, wfc_b + (size_t)l * 262144, bfc + l * nD, bufN, nullptr,
          g2 + l * nD, be2 + l * nD, nullptr, bufH);
    } else {
      // final: LN2 -> fp32 d_out
      gemm_fused<512, 1, 1><<<480, 256, 0, stream>>>(
          bufN, wfc_b + (size_t)l * 262144, bfc + l * nD, bufN, nullptr,
          g2 + l * nD, be2 + l * nD, (float*)d_out, nullptr);
    }
  }
  (void)in_sizes; (void)n_in; (void)out_size; (void)ws_size;
}